// Round 14
// baseline (392.532 us; speedup 1.0000x reference)
//
#include <hip/hip_runtime.h>
#include <hip/hip_bf16.h>
#include <stdint.h>

#define D_IN  4096
#define D_OUT 4096
#define MROWS 8192   // 2 * 4096 rows of x

using i32x4 = __attribute__((ext_vector_type(4))) int;

// -------- Kernel 1 (fused): RMSNorm -> i8 xn (per-row absmax scale)
//          AND w_q fp32 -> i8 (exact, values in {-1,0,1}) ------------------
// One row per wave (R8, at BW floor). Blocks [0,2048): 4 rows/block.
// Blocks [2048, 2048+4096): w_q conversion, coalesced.
__global__ __launch_bounds__(256) void prep_kernel(
    const float* __restrict__ x, const float* __restrict__ nw,
    signed char* __restrict__ xq, float* __restrict__ srow,
    const float* __restrict__ wq, signed char* __restrict__ wb) {
  const int b = blockIdx.x;
  const int t = threadIdx.x;

  if (b < 2048) {
    const int lane = t & 63;
    const int row  = b * 4 + (t >> 6);
    const float4* xr  = (const float4*)(x + (size_t)row * D_IN);
    const float4* nw4 = (const float4*)nw;

    float4 p[16];
    float ss = 0.f, mx = 0.f;
#pragma unroll
    for (int c = 0; c < 4; ++c) {
      float4 v[4], w[4];
#pragma unroll
      for (int i = 0; i < 4; ++i) {
        v[i] = xr[(c * 4 + i) * 64 + lane];
        w[i] = nw4[(c * 4 + i) * 64 + lane];
      }
#pragma unroll
      for (int i = 0; i < 4; ++i) {
        ss += v[i].x * v[i].x + v[i].y * v[i].y +
              v[i].z * v[i].z + v[i].w * v[i].w;
        float4 pp;
        pp.x = v[i].x * w[i].x; pp.y = v[i].y * w[i].y;
        pp.z = v[i].z * w[i].z; pp.w = v[i].w * w[i].w;
        p[c * 4 + i] = pp;
        mx = fmaxf(mx, fmaxf(fmaxf(fabsf(pp.x), fabsf(pp.y)),
                             fmaxf(fabsf(pp.z), fabsf(pp.w))));
      }
    }
#pragma unroll
    for (int off = 1; off < 64; off <<= 1) {
      ss += __shfl_xor(ss, off, 64);
      mx = fmaxf(mx, __shfl_xor(mx, off, 64));
    }
    const float scale  = rsqrtf(ss * (1.0f / D_IN) + 1e-6f);
    const float rowmax = mx * scale;
    const float s = fmaxf(rowmax, 1e-20f) * (1.0f / 127.0f);
    const float f = scale / s;   // = scale * 127 / rowmax
    if (lane == 0) srow[row] = s;

    int* out = (int*)(xq + (size_t)row * D_IN);
#pragma unroll
    for (int i = 0; i < 16; ++i) {
      const int q0 = (int)rintf(p[i].x * f);
      const int q1 = (int)rintf(p[i].y * f);
      const int q2 = (int)rintf(p[i].z * f);
      const int q3 = (int)rintf(p[i].w * f);
      out[i * 64 + lane] =
          (q0 & 0xFF) | ((q1 & 0xFF) << 8) | ((q2 & 0xFF) << 16) | (q3 << 24);
    }
  } else {
    // ---- w_q conversion, fully coalesced (proven) ----
    const int cb = b - 2048;
    const float4* w4 = (const float4*)wq;
    int* o = (int*)wb;
#pragma unroll
    for (int i = 0; i < 4; ++i) {
      const int idx = cb * 1024 + i * 256 + t;
      const float4 v = w4[idx];
      const int q0 = (int)v.x, q1 = (int)v.y, q2 = (int)v.z, q3 = (int)v.w;
      o[idx] = (q0 & 0xFF) | ((q1 & 0xFF) << 8) | ((q2 & 0xFF) << 16) | (q3 << 24);
    }
  }
}

// ---------------- Kernel 2: i8 GEMM (A: MxK, B: NxK i.e. B^T) -------------
// mfma_i32_16x16x64_i8: per lane A[m=lane&15][k=(lane>>4)*16 + j], j in [0,16).
// C/D layout (shape-determined): col=lane&15, row=(lane>>4)*4+reg.
// LDS XOR-swizzle (proven 0 conflicts): 16B chunk (row, j) at slot
// j ^ ((row>>1)&3), applied on the global source, compensated in ds_read.
//
// R14 = R5-EXACT champion skeleton (130us: 256x256 tile, 8 waves 2Mx4N,
// BKB=64, 4-deep A+B LDS ring, 1 barrier/body, WVM(4) counted waits,
// reg-level fragment double-buffer f0/f1, plain raster) with two polish
// edits:
//   1) s_setprio REMOVED from the MFMA cluster (m190: slightly negative on
//      barrier-locksteped GEMM; also removes 2 SALU from the cluster).
//   2) NON-TEMPORAL C stores: C is write-once/never-read; the 128MB write
//      stream was evicting A/B from L2/L3 (R13 falsified the dispatch-
//      order theory of the 149MB FETCH vs 48MB unique; eviction is the
//      surviving explanation). Readout: FETCH_SIZE -> 60-110MB if right.
//
// 13-round ledger: R5 reg-dbuf is the only structural win (+8%); phases
// (R2), big bodies (R3), B-from-global strided (R4) / fragment-ordered
// (R11), 32x32 MFMA (R6), pair barriers (R7), wave-role stagger (R8),
// 2 blocks/CU (R9), SGB interleave (R10), asm-MFMA (R12 FAIL), XCD
// swizzle (R13) - all neutral or negative. The residual gap to the i8
// ceiling (~70us) is the measured MFMA||LDS-port serialization under
// per-wave in-order issue; breaking it needs the full co-designed
// HK/AITER schedule, whose isolated components all measured null here.
#define BM 256
#define BN 256
#define BKB 64                  // K bytes per tile == one MFMA k-step
#define NKT (D_IN / BKB)        // 64 K-tiles
#define SLOT_BYTES (BM * BKB)   // 16 KB per ring slot per operand

#define WVM(n_) asm volatile("s_waitcnt vmcnt(" #n_ ")" ::: "memory")
#define BAR()   __builtin_amdgcn_s_barrier()

// Stage tile t_ (A+B, 2+2 global_load_lds, 16B/lane) into ring slot t_&3.
#define STAGE(t_)                                                             \
  do {                                                                        \
    _Pragma("unroll") for (int _i = 0; _i < 2; ++_i)                          \
        __builtin_amdgcn_global_load_lds(                                     \
            (__attribute__((address_space(1))) void*)(A + aOff[_i] +          \
                                                      (t_) * BKB),            \
            (__attribute__((address_space(3))) void*)&sA[(t_) & 3]            \
                                                       [ldsOff[_i]],          \
            16, 0, 0);                                                        \
    _Pragma("unroll") for (int _i = 0; _i < 2; ++_i)                          \
        __builtin_amdgcn_global_load_lds(                                     \
            (__attribute__((address_space(1))) void*)(B + bOff[_i] +          \
                                                      (t_) * BKB),            \
            (__attribute__((address_space(3))) void*)&sB[(t_) & 3]            \
                                                       [ldsOff[_i]],          \
            16, 0, 0);                                                        \
  } while (0)

// Read tile t_'s fragments from ring slot t_&3 into register arrays fa_/fb_.
#define READF(t_, fa_, fb_)                                                   \
  do {                                                                        \
    _Pragma("unroll") for (int _i = 0; _i < 8; ++_i)                          \
        fa_[_i] = *(const i32x4*)&sA[(t_) & 3][aoff0 + _i * (16 * BKB)];      \
    _Pragma("unroll") for (int _j = 0; _j < 4; ++_j)                          \
        fb_[_j] = *(const i32x4*)&sB[(t_) & 3][boff0 + _j * (16 * BKB)];      \
  } while (0)

// 32-MFMA cluster on register fragments fa_/fb_ (builtin, no setprio).
#define MFMA_C(fa_, fb_)                                                      \
  do {                                                                        \
    _Pragma("unroll") for (int _i = 0; _i < 8; ++_i)                          \
        _Pragma("unroll") for (int _j = 0; _j < 4; ++_j)                      \
            acc[_i][_j] = __builtin_amdgcn_mfma_i32_16x16x64_i8(              \
                fa_[_i], fb_[_j], acc[_i][_j], 0, 0, 0);                      \
  } while (0)

// Body T: prefetch tile T+1's fragments into fn*, stage tile T+3, compute
// tile T from fc*, counted wait (lands T+2), barrier.
#define BODY(T_, fcA_, fcB_, fnA_, fnB_, STG_, WAIT_)                         \
  do {                                                                        \
    READF((T_) + 1, fnA_, fnB_);                                              \
    STG_;                                                                     \
    MFMA_C(fcA_, fcB_);                                                       \
    WAIT_;                                                                    \
    BAR();                                                                    \
  } while (0)

__global__ __launch_bounds__(512, 2) void gemm_kernel(
    const signed char* __restrict__ A,   // MROWS x D_IN i8
    const signed char* __restrict__ B,   // D_OUT x D_IN i8
    const float* __restrict__ srow,      // MROWS   (per-row dequant scale)
    const float* __restrict__ gamma,     // D_OUT
    float* __restrict__ C) {             // MROWS x D_OUT fp32
  __shared__ __align__(16) signed char sA[4][SLOT_BYTES];  // 64 KB
  __shared__ __align__(16) signed char sB[4][SLOT_BYTES];  // 64 KB

  const int tid  = threadIdx.x;
  const int lane = tid & 63;
  const int wv   = tid >> 6;     // 0..7
  const int wm   = wv >> 2;      // 0..1: 128-row half of the 256-row tile
  const int wn   = wv & 3;       // 0..3: 64-col quarter of the 256-col tile
  const int bn   = blockIdx.x;   // 0..15  (plain raster - R13: swizzle null)
  const int bm   = blockIdx.y;   // 0..31

  i32x4 acc[8][4];
#pragma unroll
  for (int i = 0; i < 8; ++i)
#pragma unroll
    for (int j = 0; j < 4; ++j) acc[i][j] = (i32x4){0, 0, 0, 0};

  // Staging map (proven): per tile per operand 1024 chunks of 16B; chunk
  // c = i*512 + tid -> tile row r = c>>2, swizzled k-byte offset.
  size_t aOff[2], bOff[2];
  int ldsOff[2];
#pragma unroll
  for (int i = 0; i < 2; ++i) {
    const int c  = i * 512 + tid;
    const int r  = c >> 2;
    const int cc = ((c & 3) ^ ((r >> 1) & 3)) * 16;
    aOff[i] = (size_t)(bm * BM + r) * D_IN + cc;
    bOff[i] = (size_t)(bn * BN + r) * D_IN + cc;
    ldsOff[i] = (i * 512 + wv * 64) * 16;  // wave-uniform base; +lane*16 by HW
  }

  // Fragment read offsets (swizzle-compensated; row base is a multiple of
  // 16 so (row>>1)&3 == (lane>>1)&3).
  const int kk    = (((lane >> 4) ^ ((lane >> 1) & 3))) * 16;
  const int aoff0 = (wm * 128 + (lane & 15)) * BKB + kk;
  const int boff0 = (wn * 64  + (lane & 15)) * BKB + kk;

  i32x4 f0a[8], f0b[4], f1a[8], f1b[4];

  // Prologue: stage tiles 0..2; WVM(4) lands tiles 0,1 (tile 2 in flight);
  // barrier publishes; preload tile 0's fragments.
  STAGE(0); STAGE(1); STAGE(2);
  WVM(4);
  BAR();
  READF(0, f0a, f0b);

  // Main loop (2-body unroll for the f0/f1 ping-pong). Bodies 0..59.
#pragma unroll 1
  for (int T = 0; T < NKT - 4; T += 2) {
    BODY(T,     f0a, f0b, f1a, f1b, STAGE(T + 3), WVM(4));
    BODY(T + 1, f1a, f1b, f0a, f0b, STAGE(T + 4), WVM(4));
  }
  // Tail: bodies 60..63 (stages issued through tile 62 by the loop).
  BODY(60, f0a, f0b, f1a, f1b, STAGE(63), WVM(4));
  BODY(61, f1a, f1b, f0a, f0b, ,          WVM(0));   // tile 63 lands here
  // Body 62: read tile 63 (slot 3), compute 62. No further DMA.
  READF(63, f1a, f1b);
  MFMA_C(f0a, f0b);
  // Body 63.
  MFMA_C(f1a, f1b);

  // Epilogue: y = acc * srow[row] * gamma[col]. Non-temporal stores: C is
  // write-once/never-read; keep it from evicting A/B in L2/L3.
  const int col0 = bn * BN + wn * 64 + (lane & 15);
  const int row0 = bm * BM + wm * 128 + ((lane >> 4) * 4);
  float g[4];
#pragma unroll
  for (int j = 0; j < 4; ++j) g[j] = gamma[col0 + j * 16];

#pragma unroll
  for (int i = 0; i < 8; ++i) {
#pragma unroll
    for (int r = 0; r < 4; ++r) {
      const int row = row0 + i * 16 + r;
      const float sr = srow[row];
#pragma unroll
      for (int j = 0; j < 4; ++j) {
        __builtin_nontemporal_store(
            (float)acc[i][j][r] * sr * g[j],
            &C[(size_t)row * D_OUT + col0 + j * 16]);
      }
    }
  }
}

#undef BODY
#undef MFMA_C
#undef READF
#undef STAGE
#undef WVM
#undef BAR

extern "C" void kernel_launch(void* const* d_in, const int* in_sizes, int n_in,
                              void* d_out, int out_size, void* d_ws, size_t ws_size,
                              hipStream_t stream) {
  const float* x     = (const float*)d_in[0];  // (2,4096,4096)
  const float* nw    = (const float*)d_in[1];  // (4096,)
  const float* wq    = (const float*)d_in[2];  // (4096,4096) {-1,0,1}
  const float* gamma = (const float*)d_in[3];  // (4096,)
  float* y = (float*)d_out;

  // Workspace: xq i8 (32 MB) | wb i8 (16 MB) | srow fp32 (32 KB)
  signed char* xq = (signed char*)d_ws;
  signed char* wb = xq + (size_t)MROWS * D_IN;
  float* srow = (float*)(wb + (size_t)D_OUT * D_IN);

  // 2048 rmsnorm blocks (1 row/wave) + 4096 w-conversion blocks
  prep_kernel<<<2048 + 4096, 256, 0, stream>>>(x, nw, xq, srow, wq, wb);

  gemm_kernel<<<dim3(D_OUT / BN, MROWS / BM), 512, 0, stream>>>(xq, wb, srow, gamma, y);
}

// Round 15
// 383.964 us; speedup vs baseline: 1.0223x; 1.0223x over previous
//
#include <hip/hip_runtime.h>
#include <hip/hip_bf16.h>
#include <stdint.h>

#define D_IN  4096
#define D_OUT 4096
#define MROWS 8192   // 2 * 4096 rows of x

using i32x4 = __attribute__((ext_vector_type(4))) int;

// -------- Kernel 1 (fused): RMSNorm -> i8 xn (per-row absmax scale)
//          AND w_q fp32 -> i8 (exact, values in {-1,0,1}) ------------------
// One row per wave (R8, at BW floor). Blocks [0,2048): 4 rows/block.
// Blocks [2048, 2048+4096): w_q conversion, coalesced.
__global__ __launch_bounds__(256) void prep_kernel(
    const float* __restrict__ x, const float* __restrict__ nw,
    signed char* __restrict__ xq, float* __restrict__ srow,
    const float* __restrict__ wq, signed char* __restrict__ wb) {
  const int b = blockIdx.x;
  const int t = threadIdx.x;

  if (b < 2048) {
    const int lane = t & 63;
    const int row  = b * 4 + (t >> 6);
    const float4* xr  = (const float4*)(x + (size_t)row * D_IN);
    const float4* nw4 = (const float4*)nw;

    float4 p[16];
    float ss = 0.f, mx = 0.f;
#pragma unroll
    for (int c = 0; c < 4; ++c) {
      float4 v[4], w[4];
#pragma unroll
      for (int i = 0; i < 4; ++i) {
        v[i] = xr[(c * 4 + i) * 64 + lane];
        w[i] = nw4[(c * 4 + i) * 64 + lane];
      }
#pragma unroll
      for (int i = 0; i < 4; ++i) {
        ss += v[i].x * v[i].x + v[i].y * v[i].y +
              v[i].z * v[i].z + v[i].w * v[i].w;
        float4 pp;
        pp.x = v[i].x * w[i].x; pp.y = v[i].y * w[i].y;
        pp.z = v[i].z * w[i].z; pp.w = v[i].w * w[i].w;
        p[c * 4 + i] = pp;
        mx = fmaxf(mx, fmaxf(fmaxf(fabsf(pp.x), fabsf(pp.y)),
                             fmaxf(fabsf(pp.z), fabsf(pp.w))));
      }
    }
#pragma unroll
    for (int off = 1; off < 64; off <<= 1) {
      ss += __shfl_xor(ss, off, 64);
      mx = fmaxf(mx, __shfl_xor(mx, off, 64));
    }
    const float scale  = rsqrtf(ss * (1.0f / D_IN) + 1e-6f);
    const float rowmax = mx * scale;
    const float s = fmaxf(rowmax, 1e-20f) * (1.0f / 127.0f);
    const float f = scale / s;   // = scale * 127 / rowmax
    if (lane == 0) srow[row] = s;

    int* out = (int*)(xq + (size_t)row * D_IN);
#pragma unroll
    for (int i = 0; i < 16; ++i) {
      const int q0 = (int)rintf(p[i].x * f);
      const int q1 = (int)rintf(p[i].y * f);
      const int q2 = (int)rintf(p[i].z * f);
      const int q3 = (int)rintf(p[i].w * f);
      out[i * 64 + lane] =
          (q0 & 0xFF) | ((q1 & 0xFF) << 8) | ((q2 & 0xFF) << 16) | (q3 << 24);
    }
  } else {
    // ---- w_q conversion, fully coalesced (proven) ----
    const int cb = b - 2048;
    const float4* w4 = (const float4*)wq;
    int* o = (int*)wb;
#pragma unroll
    for (int i = 0; i < 4; ++i) {
      const int idx = cb * 1024 + i * 256 + t;
      const float4 v = w4[idx];
      const int q0 = (int)v.x, q1 = (int)v.y, q2 = (int)v.z, q3 = (int)v.w;
      o[idx] = (q0 & 0xFF) | ((q1 & 0xFF) << 8) | ((q2 & 0xFF) << 16) | (q3 << 24);
    }
  }
}

// ---------------- Kernel 2: i8 GEMM (A: MxK, B: NxK i.e. B^T) -------------
// mfma_i32_16x16x64_i8: per lane A[m=lane&15][k=(lane>>4)*16 + j], j in [0,16).
// C/D layout (shape-determined): col=lane&15, row=(lane>>4)*4+reg.
// LDS XOR-swizzle (proven 0 conflicts): 16B chunk (row, j) at slot
// j ^ ((row>>1)&3), applied on the global source, compensated in ds_read.
//
// R15 = R5 CHAMPION RESTORED BYTE-EXACT (130us gemm, 45% MfmaUtil).
// 256x256 tile, 8 waves 2Mx4N, BKB=64, 4-deep A+B LDS ring, 1 barrier per
// body, WVM(4) counted waits (never drains to 0 in the main loop), reg
// fragment double-buffer f0/f1 (read T+1 while computing T), setprio(1)
// around the MFMA cluster (load-bearing here: both no-setprio rounds cost
// 3-12% - R14 lesson: technique signs are structure-conditional BOTH ways),
// plain raster, regular stores.
//
// 14-round ledger (all measured, absmax-exact unless noted):
//   R5 reg-dbuf: +8% (the one structural win)  -> 130us
//   R2 phase-split 176 / R3 big-body 161 / R4 B-reg strided 204 /
//   R6 32x32-MFMA 178 (bank conflicts) / R7 pair-barriers 146 /
//   R8 wave-stagger 132 / R9 2-blocks-CU 170 / R10 SGB 133 /
//   R11 B-reg fragment-ordered 147 / R12 asm-MFMA FAIL(NaN) /
//   R13 XCD-swizzle 131-136, FETCH unchanged / R14 no-setprio+nt-store 146.
// Residual gap to the i8 MFMA ceiling (~70us): measured MFMA||LDS-port
// serialization (slot 2437cyc = 1280 MFMA + 1150 LDS, additive) under
// per-wave in-order issue; every isolated plain-HIP lever is null here.
#define BM 256
#define BN 256
#define BKB 64                  // K bytes per tile == one MFMA k-step
#define NKT (D_IN / BKB)        // 64 K-tiles
#define SLOT_BYTES (BM * BKB)   // 16 KB per ring slot per operand

#define WVM(n_) asm volatile("s_waitcnt vmcnt(" #n_ ")" ::: "memory")
#define BAR()   __builtin_amdgcn_s_barrier()

// Stage tile t_ (A+B, 2+2 global_load_lds, 16B/lane) into ring slot t_&3.
#define STAGE(t_)                                                             \
  do {                                                                        \
    _Pragma("unroll") for (int _i = 0; _i < 2; ++_i)                          \
        __builtin_amdgcn_global_load_lds(                                     \
            (__attribute__((address_space(1))) void*)(A + aOff[_i] +          \
                                                      (t_) * BKB),            \
            (__attribute__((address_space(3))) void*)&sA[(t_) & 3]            \
                                                       [ldsOff[_i]],          \
            16, 0, 0);                                                        \
    _Pragma("unroll") for (int _i = 0; _i < 2; ++_i)                          \
        __builtin_amdgcn_global_load_lds(                                     \
            (__attribute__((address_space(1))) void*)(B + bOff[_i] +          \
                                                      (t_) * BKB),            \
            (__attribute__((address_space(3))) void*)&sB[(t_) & 3]            \
                                                       [ldsOff[_i]],          \
            16, 0, 0);                                                        \
  } while (0)

// Read tile t_'s fragments from ring slot t_&3 into register arrays fa_/fb_.
#define READF(t_, fa_, fb_)                                                   \
  do {                                                                        \
    _Pragma("unroll") for (int _i = 0; _i < 8; ++_i)                          \
        fa_[_i] = *(const i32x4*)&sA[(t_) & 3][aoff0 + _i * (16 * BKB)];      \
    _Pragma("unroll") for (int _j = 0; _j < 4; ++_j)                          \
        fb_[_j] = *(const i32x4*)&sB[(t_) & 3][boff0 + _j * (16 * BKB)];      \
  } while (0)

// 32-MFMA cluster on register fragments fa_/fb_ (builtin + setprio).
#define MFMA_C(fa_, fb_)                                                      \
  do {                                                                        \
    __builtin_amdgcn_s_setprio(1);                                            \
    _Pragma("unroll") for (int _i = 0; _i < 8; ++_i)                          \
        _Pragma("unroll") for (int _j = 0; _j < 4; ++_j)                      \
            acc[_i][_j] = __builtin_amdgcn_mfma_i32_16x16x64_i8(              \
                fa_[_i], fb_[_j], acc[_i][_j], 0, 0, 0);                      \
    __builtin_amdgcn_s_setprio(0);                                            \
  } while (0)

// Body T: prefetch tile T+1's fragments into fn*, stage tile T+3, compute
// tile T from fc*, counted wait (lands T+2), barrier.
#define BODY(T_, fcA_, fcB_, fnA_, fnB_, STG_, WAIT_)                         \
  do {                                                                        \
    READF((T_) + 1, fnA_, fnB_);                                              \
    STG_;                                                                     \
    MFMA_C(fcA_, fcB_);                                                       \
    WAIT_;                                                                    \
    BAR();                                                                    \
  } while (0)

__global__ __launch_bounds__(512, 2) void gemm_kernel(
    const signed char* __restrict__ A,   // MROWS x D_IN i8
    const signed char* __restrict__ B,   // D_OUT x D_IN i8
    const float* __restrict__ srow,      // MROWS   (per-row dequant scale)
    const float* __restrict__ gamma,     // D_OUT
    float* __restrict__ C) {             // MROWS x D_OUT fp32
  __shared__ __align__(16) signed char sA[4][SLOT_BYTES];  // 64 KB
  __shared__ __align__(16) signed char sB[4][SLOT_BYTES];  // 64 KB

  const int tid  = threadIdx.x;
  const int lane = tid & 63;
  const int wv   = tid >> 6;     // 0..7
  const int wm   = wv >> 2;      // 0..1: 128-row half of the 256-row tile
  const int wn   = wv & 3;       // 0..3: 64-col quarter of the 256-col tile
  const int bn   = blockIdx.x;   // 0..15
  const int bm   = blockIdx.y;   // 0..31

  i32x4 acc[8][4];
#pragma unroll
  for (int i = 0; i < 8; ++i)
#pragma unroll
    for (int j = 0; j < 4; ++j) acc[i][j] = (i32x4){0, 0, 0, 0};

  // Staging map (proven): per tile per operand 1024 chunks of 16B; chunk
  // c = i*512 + tid -> tile row r = c>>2, swizzled k-byte offset.
  size_t aOff[2], bOff[2];
  int ldsOff[2];
#pragma unroll
  for (int i = 0; i < 2; ++i) {
    const int c  = i * 512 + tid;
    const int r  = c >> 2;
    const int cc = ((c & 3) ^ ((r >> 1) & 3)) * 16;
    aOff[i] = (size_t)(bm * BM + r) * D_IN + cc;
    bOff[i] = (size_t)(bn * BN + r) * D_IN + cc;
    ldsOff[i] = (i * 512 + wv * 64) * 16;  // wave-uniform base; +lane*16 by HW
  }

  // Fragment read offsets (swizzle-compensated; row base is a multiple of
  // 16 so (row>>1)&3 == (lane>>1)&3).
  const int kk    = (((lane >> 4) ^ ((lane >> 1) & 3))) * 16;
  const int aoff0 = (wm * 128 + (lane & 15)) * BKB + kk;
  const int boff0 = (wn * 64  + (lane & 15)) * BKB + kk;

  i32x4 f0a[8], f0b[4], f1a[8], f1b[4];

  // Prologue: stage tiles 0..2; WVM(4) lands tiles 0,1 (tile 2 in flight);
  // barrier publishes; preload tile 0's fragments.
  STAGE(0); STAGE(1); STAGE(2);
  WVM(4);
  BAR();
  READF(0, f0a, f0b);

  // Main loop (2-body unroll for the f0/f1 ping-pong). Bodies 0..59.
#pragma unroll 1
  for (int T = 0; T < NKT - 4; T += 2) {
    BODY(T,     f0a, f0b, f1a, f1b, STAGE(T + 3), WVM(4));
    BODY(T + 1, f1a, f1b, f0a, f0b, STAGE(T + 4), WVM(4));
  }
  // Tail: bodies 60..63 (stages issued through tile 62 by the loop).
  BODY(60, f0a, f0b, f1a, f1b, STAGE(63), WVM(4));
  BODY(61, f1a, f1b, f0a, f0b, ,          WVM(0));   // tile 63 lands here
  // Body 62: read tile 63 (slot 3), compute 62. No further DMA.
  READF(63, f1a, f1b);
  MFMA_C(f0a, f0b);
  // Body 63.
  MFMA_C(f1a, f1b);

  // Epilogue: y = acc * srow[row] * gamma[col]
  const int col0 = bn * BN + wn * 64 + (lane & 15);
  const int row0 = bm * BM + wm * 128 + ((lane >> 4) * 4);
  float g[4];
#pragma unroll
  for (int j = 0; j < 4; ++j) g[j] = gamma[col0 + j * 16];

#pragma unroll
  for (int i = 0; i < 8; ++i) {
#pragma unroll
    for (int r = 0; r < 4; ++r) {
      const int row = row0 + i * 16 + r;
      const float sr = srow[row];
#pragma unroll
      for (int j = 0; j < 4; ++j) {
        C[(size_t)row * D_OUT + col0 + j * 16] =
            (float)acc[i][j][r] * sr * g[j];
      }
    }
  }
}

#undef BODY
#undef MFMA_C
#undef READF
#undef STAGE
#undef WVM
#undef BAR

extern "C" void kernel_launch(void* const* d_in, const int* in_sizes, int n_in,
                              void* d_out, int out_size, void* d_ws, size_t ws_size,
                              hipStream_t stream) {
  const float* x     = (const float*)d_in[0];  // (2,4096,4096)
  const float* nw    = (const float*)d_in[1];  // (4096,)
  const float* wq    = (const float*)d_in[2];  // (4096,4096) {-1,0,1}
  const float* gamma = (const float*)d_in[3];  // (4096,)
  float* y = (float*)d_out;

  // Workspace: xq i8 (32 MB) | wb i8 (16 MB) | srow fp32 (32 KB)
  signed char* xq = (signed char*)d_ws;
  signed char* wb = xq + (size_t)MROWS * D_IN;
  float* srow = (float*)(wb + (size_t)D_OUT * D_IN);

  // 2048 rmsnorm blocks (1 row/wave) + 4096 w-conversion blocks
  prep_kernel<<<2048 + 4096, 256, 0, stream>>>(x, nw, xq, srow, wq, wb);

  gemm_kernel<<<dim3(D_OUT / BN, MROWS / BM), 512, 0, stream>>>(xq, wb, srow, gamma, y);
}